// Round 16
// baseline (47.970 us; speedup 1.0000x reference)
//
#include <hip/hip_runtime.h>
#include <stdint.h>

#define B 512
#define D 128
#define HALFC 131072u
#define NPART 8192  /* 512 rows x 16 wave-slots */

__device__ __forceinline__ uint32_t rotl32(uint32_t x, uint32_t r) {
  return (x << r) | (x >> (32u - r));
}

// Exact JAX/XLA threefry2x32 (20 rounds, key-schedule injections every 4).
__device__ __forceinline__ void threefry2x32(uint32_t k0, uint32_t k1,
                                             uint32_t x0, uint32_t x1,
                                             uint32_t& y0, uint32_t& y1) {
  uint32_t k2 = k0 ^ k1 ^ 0x1BD11BDAu;
  x0 += k0; x1 += k1;
#define TF_R(r) { x0 += x1; x1 = rotl32(x1, r); x1 ^= x0; }
  TF_R(13) TF_R(15) TF_R(26) TF_R(6)
  x0 += k1; x1 += k2 + 1u;
  TF_R(17) TF_R(29) TF_R(16) TF_R(24)
  x0 += k2; x1 += k0 + 2u;
  TF_R(13) TF_R(15) TF_R(26) TF_R(6)
  x0 += k0; x1 += k1 + 3u;
  TF_R(17) TF_R(29) TF_R(16) TF_R(24)
  x0 += k1; x1 += k2 + 4u;
  TF_R(13) TF_R(15) TF_R(26) TF_R(6)
  x0 += k2; x1 += k0 + 5u;
#undef TF_R
  y0 = x0; y1 = x1;
}

// N independent threefry chains, fully unrolled in registers.
template <int N>
__device__ __forceinline__ void tf_multi(uint32_t k0, uint32_t k1,
                                         uint32_t (&x0)[N], uint32_t (&x1)[N]) {
  uint32_t k2 = k0 ^ k1 ^ 0x1BD11BDAu;
#pragma unroll
  for (int q = 0; q < N; ++q) { x0[q] += k0; x1[q] += k1; }
#define TFM_R(r) \
  _Pragma("unroll") for (int q = 0; q < N; ++q) { \
    x0[q] += x1[q]; x1[q] = rotl32(x1[q], r); x1[q] ^= x0[q]; }
#define TFM_INJ(a, b, c) \
  _Pragma("unroll") for (int q = 0; q < N; ++q) { x0[q] += a; x1[q] += b + c; }
  TFM_R(13) TFM_R(15) TFM_R(26) TFM_R(6)
  TFM_INJ(k1, k2, 1u)
  TFM_R(17) TFM_R(29) TFM_R(16) TFM_R(24)
  TFM_INJ(k2, k0, 2u)
  TFM_R(13) TFM_R(15) TFM_R(26) TFM_R(6)
  TFM_INJ(k0, k1, 3u)
  TFM_R(17) TFM_R(29) TFM_R(16) TFM_R(24)
  TFM_INJ(k1, k2, 4u)
  TFM_R(13) TFM_R(15) TFM_R(26) TFM_R(6)
  TFM_INJ(k2, k0, 5u)
#undef TFM_R
#undef TFM_INJ
}

// 64-lane max-reduce via DPP: row_shr 1/2/4/8 then row_bcast 15/31.
__device__ __forceinline__ uint32_t dpp_max_all(uint32_t x) {
  uint32_t t;
#define DPP_STEP(ctrl) \
  t = (uint32_t)__builtin_amdgcn_update_dpp(0, (int)x, ctrl, 0xf, 0xf, true); \
  x = (t > x) ? t : x;
  DPP_STEP(0x111)  // row_shr:1
  DPP_STEP(0x112)  // row_shr:2
  DPP_STEP(0x114)  // row_shr:4
  DPP_STEP(0x118)  // row_shr:8
  DPP_STEP(0x142)  // row_bcast:15
  DPP_STEP(0x143)  // row_bcast:31
#undef DPP_STEP
  return (uint32_t)__builtin_amdgcn_readlane((int)x, 63);
}

// K1: tiled dist "GEMM" (unchanged). Block 0 computes the 512 anchor keys.
__global__ __launch_bounds__(256) void dist_kernel(
    const float* __restrict__ emb, float* __restrict__ dist,
    uint32_t* __restrict__ keys0, uint32_t* __restrict__ keys1) {
  __shared__ float As[32][132];
  __shared__ float Bs[32][132];
  __shared__ float sqa[32], sqb[32];
  int bid = blockIdx.x;
  int ti = bid >> 4, tj = bid & 15;
  int t = threadIdx.x;

  const float4* ga = reinterpret_cast<const float4*>(emb + (size_t)ti * 32 * D);
  const float4* gb = reinterpret_cast<const float4*>(emb + (size_t)tj * 32 * D);
  #pragma unroll
  for (int k = 0; k < 4; ++k) {
    int idx = t + k * 256;
    int r = idx >> 5;
    int c4 = idx & 31;
    *reinterpret_cast<float4*>(&As[r][c4 * 4]) = ga[idx];
    *reinterpret_cast<float4*>(&Bs[r][c4 * 4]) = gb[idx];
  }
  __syncthreads();

  {
    int row = t >> 2, seg = t & 3;
    const float* src = (row < 32) ? &As[row][seg * 32] : &Bs[row - 32][seg * 32];
    float s = 0.f;
    #pragma unroll
    for (int m = 0; m < 32; ++m) { float v = src[m]; s += v * v; }
    s += __shfl_xor(s, 1);
    s += __shfl_xor(s, 2);
    if (seg == 0) { if (row < 32) sqa[row] = s; else sqb[row - 32] = s; }
  }

  int r = t >> 3, g = t & 7;
  const float4* A4 = reinterpret_cast<const float4*>(&As[r][0]);
  const float4* B0 = reinterpret_cast<const float4*>(&Bs[g][0]);
  const float4* B1 = reinterpret_cast<const float4*>(&Bs[g + 8][0]);
  const float4* B2 = reinterpret_cast<const float4*>(&Bs[g + 16][0]);
  const float4* B3 = reinterpret_cast<const float4*>(&Bs[g + 24][0]);
  float acc0 = 0.f, acc1 = 0.f, acc2 = 0.f, acc3 = 0.f;
  #pragma unroll 8
  for (int k4 = 0; k4 < 32; ++k4) {
    float4 a = A4[k4];
    float4 b0 = B0[k4], b1 = B1[k4], b2 = B2[k4], b3 = B3[k4];
    acc0 += a.x * b0.x + a.y * b0.y + a.z * b0.z + a.w * b0.w;
    acc1 += a.x * b1.x + a.y * b1.y + a.z * b1.z + a.w * b1.w;
    acc2 += a.x * b2.x + a.y * b2.y + a.z * b2.z + a.w * b2.w;
    acc3 += a.x * b3.x + a.y * b3.y + a.z * b3.z + a.w * b3.w;
  }
  __syncthreads();
  float sa = sqa[r];
  float* drow = dist + (size_t)(ti * 32 + r) * B + tj * 32;
  drow[g]      = sqrtf(fmaxf(sa + sqb[g]      - 2.f * acc0, 0.f));
  drow[g + 8]  = sqrtf(fmaxf(sa + sqb[g + 8]  - 2.f * acc1, 0.f));
  drow[g + 16] = sqrtf(fmaxf(sa + sqb[g + 16] - 2.f * acc2, 0.f));
  drow[g + 24] = sqrtf(fmaxf(sa + sqb[g + 24] - 2.f * acc3, 0.f));

  if (bid == 0) {
    #pragma unroll
    for (int pp = 0; pp < 2; ++pp) {
      int p = t + pp * 256;
      uint32_t i0 = 2u * (uint32_t)p, i1 = i0 + 1u;
      uint32_t a0, a1, b0, b1;
      if (p < 256) {
        threefry2x32(0u, 42u, i0, i0 + 512u, a0, a1);
        threefry2x32(0u, 42u, i1, i1 + 512u, b0, b1);
        keys0[p] = a0; keys1[p] = b0;
      } else {
        threefry2x32(0u, 42u, i0 - 512u, i0, a0, a1);
        threefry2x32(0u, 42u, i1 - 512u, i1, b0, b1);
        keys0[p] = a1; keys1[p] = b1;
      }
    }
  }
}

// K2 prep: one block per row. Builds the row's bucket-ordered packed-key
// array (skey_g), packed bucket ranges (range_g: start<<16|end), and hard_d.
// Block 0 additionally builds the per-label anchor lists.
__global__ __launch_bounds__(512) void prep_kernel(
    const float* __restrict__ dist, const int* __restrict__ labels,
    unsigned long long* __restrict__ skey_g, uint32_t* __restrict__ range_g,
    float* __restrict__ hard_d_g, unsigned short* __restrict__ lists,
    int* __restrict__ lcount) {
  __shared__ uint32_t hist[B];
  __shared__ uint32_t cur[B];
  __shared__ uint32_t wsum32[8], wprefix[8];
  __shared__ unsigned long long wmin[8];
  __shared__ unsigned short slab[B];
  int i = blockIdx.x;
  int t = threadIdx.x;
  int wave = t >> 6, lane = t & 63;
  hist[t] = 0u;
  slab[t] = (unsigned short)labels[t];
  float dv = dist[(size_t)i * B + t];
  __syncthreads();
  unsigned short lab_i = slab[i];
  bool neg = (slab[t] != lab_i);
  int b_t = (int)fminf(fmaxf(dv * 16.0f, 0.0f), 511.0f);
  if (neg) atomicAdd(&hist[b_t], 1u);
  // hard-negative argmin (ties -> lowest col): packed (fbits<<9 | col), min
  unsigned long long hkey =
      neg ? ((((unsigned long long)__float_as_uint(dv)) << 9) | (unsigned)t)
          : ~0ull;
  #pragma unroll
  for (int off = 32; off; off >>= 1) {
    unsigned long long o = __shfl_xor(hkey, off);
    if (o < hkey) hkey = o;
  }
  if (lane == 0) wmin[wave] = hkey;
  __syncthreads();  // hist + wmin ready
  if (t == 0) {
    unsigned long long m = wmin[0];
    #pragma unroll
    for (int w = 1; w < 8; ++w)
      if (wmin[w] < m) m = wmin[w];
    hard_d_g[i] = __uint_as_float((uint32_t)(m >> 9));  // NaN iff no negatives
  }
  // block-wide inclusive scan of hist
  uint32_t v = hist[t];
  #pragma unroll
  for (int d = 1; d < 64; d <<= 1) {
    uint32_t u = __shfl_up(v, d);
    if (lane >= (unsigned)d) v += u;
  }
  if (lane == 63) wsum32[wave] = v;
  __syncthreads();
  if (t == 0) {
    uint32_t acc = 0;
    #pragma unroll
    for (int w = 0; w < 8; ++w) { wprefix[w] = acc; acc += wsum32[w]; }
  }
  __syncthreads();
  uint32_t inc = v + wprefix[wave];
  uint32_t st = inc - hist[t];
  cur[t] = st;
  range_g[(size_t)i * B + t] = (st << 16) | inc;  // excl start | incl end
  __syncthreads();
  // scatter packed keys bucket-ordered (in-bucket order irrelevant:
  // selection is an order-independent max over unique packed keys)
  if (neg) {
    uint32_t pos = atomicAdd(&cur[b_t], 1u);
    skey_g[(size_t)i * B + pos] =
        (((unsigned long long)__float_as_uint(dv)) << 9) | (unsigned)t;
  }
  // block 0: per-label ascending anchor lists (wave w -> label w)
  if (i == 0) {
    unsigned long long lmask_lt = (1ull << lane) - 1ull;
    int n = 0;
    #pragma unroll
    for (int c = 0; c < 8; ++c) {
      int r = c * 64 + lane;
      bool vv = (slab[r] == (unsigned short)wave);
      unsigned long long mk = __ballot(vv);
      if (vv) lists[wave * B + n + __popcll(mk & lmask_lt)] = (unsigned short)r;
      n += __popcll(mk);
    }
    if (lane == 0) lcount[wave] = (n == B) ? 0 : n;  // n==B -> no negatives
  }
}

// K3 triplet: pure-wave, ZERO LDS, ZERO barriers. 8192 independent waves;
// wave (row i, slot s) walks anchors k = s, s+16, ... of i's label list.
// All row data (skey/range/dist/hard_d) read from L2; anchors independent,
// so the compiler can overlap whole iterations.
__global__ __launch_bounds__(256) void triplet_kernel(
    const float* __restrict__ dist, const int* __restrict__ labels,
    const uint32_t* __restrict__ keys0, const uint32_t* __restrict__ keys1,
    const unsigned long long* __restrict__ skey_g,
    const uint32_t* __restrict__ range_g, const float* __restrict__ hard_d_g,
    const unsigned short* __restrict__ lists, const int* __restrict__ lcount,
    double* __restrict__ partials, int* __restrict__ pcnt) {
  int wave = threadIdx.x >> 6, lane = threadIdx.x & 63;
  int slot = blockIdx.x * 4 + wave;
  int i = slot >> 4;
  int s = slot & 15;
  int lab = labels[i];
  int nlist = lcount[lab];
  const unsigned short* __restrict__ mylist = lists + lab * B;
  const unsigned long long* __restrict__ skey = skey_g + (size_t)i * B;
  const uint32_t* __restrict__ range = range_g + (size_t)i * B;
  const float* __restrict__ drow = dist + (size_t)i * B;
  float hard_d = hard_d_g[i];
  uint32_t rowbase = (uint32_t)((i & 255) * B);
  bool take_hi = (i >= 256);
  double wsum = 0.0;
  unsigned int wcnt = 0;

#define LOAD_ANCHOR(KK, KP0, KP1, PD, ST, EN, LOK, HIK) { \
    int p_ = __builtin_amdgcn_readfirstlane((int)mylist[KK]); \
    KP0 = keys0[p_]; KP1 = keys1[p_]; \
    PD = (p_ == i) ? -2.0f : drow[p_]; /* sentinel: empty window */ \
    float hf_ = PD + 1.0f; /* margin = 1.0 */ \
    int lob_ = (int)fminf(fmaxf(PD * 16.0f, 0.0f), 511.0f); \
    int hib_ = (int)fminf(fmaxf(hf_ * 16.0f, 0.0f), 511.0f); \
    ST = (int)(range[lob_] >> 16); \
    EN = (int)(range[hib_] & 0xFFFFu); \
    LOK = (((unsigned long long)__float_as_uint(PD)) << 9) | 511u; \
    HIK = ((unsigned long long)__float_as_uint(hf_)) << 9; }

// One drain step of NCH chains starting at superset index c0 (+64 per chain).
#define DRAIN(NCH) { \
    uint32_t xs0[NCH], xs1[NCH], js[NCH]; bool vd[NCH]; \
    _Pragma("unroll") for (int q = 0; q < NCH; ++q) { \
      int c_ = c0 + q * 64; \
      unsigned long long kv = skey[(c_ < end) ? c_ : start]; \
      vd[q] = (c_ < end) && (kv > lokey) && (kv < hikey); \
      js[q] = (uint32_t)(kv & 0x1FFu); \
      xs0[q] = rowbase + js[q]; \
      xs1[q] = rowbase + js[q] + HALFC; \
    } \
    tf_multi<NCH>(kp0, kp1, xs0, xs1); \
    _Pragma("unroll") for (int q = 0; q < NCH; ++q) { \
      uint32_t kk = ((take_hi ? xs1[q] : xs0[q]) & 0xFFFFFE00u) | \
                    (511u - js[q]); \
      if (vd[q] && kk > best) best = kk; \
    } }

  int k = s;
  uint32_t kpN0 = 0, kpN1 = 0;
  float pdN = -2.0f;
  int stN = 0, enN = 0;
  unsigned long long lokN = 0, hikN = 0;
  if (k < nlist) LOAD_ANCHOR(k, kpN0, kpN1, pdN, stN, enN, lokN, hikN);

  while (k < nlist) {
    uint32_t kp0 = kpN0, kp1 = kpN1;
    float pos_d = pdN;
    int start = stN, end = enN;
    unsigned long long lokey = lokN, hikey = hikN;
    int kn = k + 16;
    if (kn < nlist) LOAD_ANCHOR(kn, kpN0, kpN1, pdN, stN, enN, lokN, hikN);

    float tl;
    if (end > start) {
      // packed key: (bits23 << 9) | (511 - j); max -> max bits, tie -> min j
      uint32_t best = 0u;
      int nch = (end - start + 63) >> 6;  // wave-uniform
      int c0 = start + lane;
      while (nch > 4) { DRAIN(4); c0 += 256; nch -= 4; }
      switch (nch) {
        case 4: DRAIN(4); break;
        case 3: DRAIN(3); break;
        case 2: DRAIN(2); break;
        default: DRAIN(1); break;
      }
      best = dpp_max_all(best);
      if (best) {
        int idx = 511 - (int)(best & 0x1FFu);
        tl = pos_d - drow[idx] + 1.0f;
      } else {
        tl = pos_d - hard_d + 1.0f;
      }
    } else {
      tl = pos_d - hard_d + 1.0f;  // sentinel pos_d=-2 -> tl<0, dropped
    }
    if (tl > 0.f) { wsum += (double)tl; wcnt++; }
    k = kn;
  }
#undef LOAD_ANCHOR
#undef DRAIN

  if (lane == 0) {
    partials[slot] = wsum;
    pcnt[slot] = (int)wcnt;
  }
}

// K4: deterministic fixed-order reduction of the 8192 wave partials.
__global__ __launch_bounds__(256) void finalize_kernel(
    const double* __restrict__ partials, const int* __restrict__ pcnt,
    float* __restrict__ out) {
  __shared__ double ss[256];
  __shared__ int sc[256];
  int t = threadIdx.x;
  double s = 0.0;
  int c = 0;
  for (int k = t; k < NPART; k += 256) { s += partials[k]; c += pcnt[k]; }
  ss[t] = s; sc[t] = c;
  __syncthreads();
  for (int st = 128; st; st >>= 1) {
    if (t < st) { ss[t] += ss[t + st]; sc[t] += sc[t + st]; }
    __syncthreads();
  }
  if (t == 0) out[0] = sc[0] ? (float)(ss[0] / (double)sc[0]) : 0.0f;
}

extern "C" void kernel_launch(void* const* d_in, const int* in_sizes, int n_in,
                              void* d_out, int out_size, void* d_ws, size_t ws_size,
                              hipStream_t stream) {
  const float* emb = (const float*)d_in[0];
  const int* labels = (const int*)d_in[1];
  float* out = (float*)d_out;
  char* ws = (char*)d_ws;

  float* dist = (float*)ws;                                   // 1 MB
  unsigned long long* skey_g = (unsigned long long*)(ws + (1u << 20));  // 2 MB
  uint32_t* range_g = (uint32_t*)(ws + 3 * (1u << 20));       // 1 MB
  uint32_t* keys0 = (uint32_t*)(ws + 4 * (1u << 20));         // 2 KB
  uint32_t* keys1 = (uint32_t*)(ws + 4 * (1u << 20) + 2048);  // 2 KB
  unsigned short* lists = (unsigned short*)(ws + 4 * (1u << 20) + 4096);  // 8 KB
  int* lcount = (int*)(ws + 4 * (1u << 20) + 12288);          // 64 B
  float* hard_d_g = (float*)(ws + 4 * (1u << 20) + 12352);    // 2 KB
  double* partials = (double*)(ws + 4 * (1u << 20) + 16384);  // 64 KB
  int* pcnt = (int*)(ws + 4 * (1u << 20) + 16384 + 65536);    // 32 KB

  dist_kernel<<<256, 256, 0, stream>>>(emb, dist, keys0, keys1);
  prep_kernel<<<B, 512, 0, stream>>>(dist, labels, skey_g, range_g, hard_d_g,
                                     lists, lcount);
  triplet_kernel<<<2048, 256, 0, stream>>>(dist, labels, keys0, keys1, skey_g,
                                           range_g, hard_d_g, lists, lcount,
                                           partials, pcnt);
  finalize_kernel<<<1, 256, 0, stream>>>(partials, pcnt, out);
}

// Round 17
// 47.957 us; speedup vs baseline: 1.0003x; 1.0003x over previous
//
#include <hip/hip_runtime.h>
#include <stdint.h>

#define B 512
#define D 128
#define HALFC 131072u
#define NPART 8192  /* 512 rows x 16 wave-slots */

__device__ __forceinline__ uint32_t rotl32(uint32_t x, uint32_t r) {
  return (x << r) | (x >> (32u - r));
}

// Exact JAX/XLA threefry2x32 (20 rounds, key-schedule injections every 4).
__device__ __forceinline__ void threefry2x32(uint32_t k0, uint32_t k1,
                                             uint32_t x0, uint32_t x1,
                                             uint32_t& y0, uint32_t& y1) {
  uint32_t k2 = k0 ^ k1 ^ 0x1BD11BDAu;
  x0 += k0; x1 += k1;
#define TF_R(r) { x0 += x1; x1 = rotl32(x1, r); x1 ^= x0; }
  TF_R(13) TF_R(15) TF_R(26) TF_R(6)
  x0 += k1; x1 += k2 + 1u;
  TF_R(17) TF_R(29) TF_R(16) TF_R(24)
  x0 += k2; x1 += k0 + 2u;
  TF_R(13) TF_R(15) TF_R(26) TF_R(6)
  x0 += k0; x1 += k1 + 3u;
  TF_R(17) TF_R(29) TF_R(16) TF_R(24)
  x0 += k1; x1 += k2 + 4u;
  TF_R(13) TF_R(15) TF_R(26) TF_R(6)
  x0 += k2; x1 += k0 + 5u;
#undef TF_R
  y0 = x0; y1 = x1;
}

// N independent threefry chains, fully unrolled in registers.
template <int N>
__device__ __forceinline__ void tf_multi(uint32_t k0, uint32_t k1,
                                         uint32_t (&x0)[N], uint32_t (&x1)[N]) {
  uint32_t k2 = k0 ^ k1 ^ 0x1BD11BDAu;
#pragma unroll
  for (int q = 0; q < N; ++q) { x0[q] += k0; x1[q] += k1; }
#define TFM_R(r) \
  _Pragma("unroll") for (int q = 0; q < N; ++q) { \
    x0[q] += x1[q]; x1[q] = rotl32(x1[q], r); x1[q] ^= x0[q]; }
#define TFM_INJ(a, b, c) \
  _Pragma("unroll") for (int q = 0; q < N; ++q) { x0[q] += a; x1[q] += b + c; }
  TFM_R(13) TFM_R(15) TFM_R(26) TFM_R(6)
  TFM_INJ(k1, k2, 1u)
  TFM_R(17) TFM_R(29) TFM_R(16) TFM_R(24)
  TFM_INJ(k2, k0, 2u)
  TFM_R(13) TFM_R(15) TFM_R(26) TFM_R(6)
  TFM_INJ(k0, k1, 3u)
  TFM_R(17) TFM_R(29) TFM_R(16) TFM_R(24)
  TFM_INJ(k1, k2, 4u)
  TFM_R(13) TFM_R(15) TFM_R(26) TFM_R(6)
  TFM_INJ(k2, k0, 5u)
#undef TFM_R
#undef TFM_INJ
}

// 64-lane max-reduce via DPP: row_shr 1/2/4/8 then row_bcast 15/31.
__device__ __forceinline__ uint32_t dpp_max_all(uint32_t x) {
  uint32_t t;
#define DPP_STEP(ctrl) \
  t = (uint32_t)__builtin_amdgcn_update_dpp(0, (int)x, ctrl, 0xf, 0xf, true); \
  x = (t > x) ? t : x;
  DPP_STEP(0x111)  // row_shr:1
  DPP_STEP(0x112)  // row_shr:2
  DPP_STEP(0x114)  // row_shr:4
  DPP_STEP(0x118)  // row_shr:8
  DPP_STEP(0x142)  // row_bcast:15
  DPP_STEP(0x143)  // row_bcast:31
#undef DPP_STEP
  return (uint32_t)__builtin_amdgcn_readlane((int)x, 63);
}

// K1: tiled dist "GEMM" (unchanged). Block 0 computes the 512 anchor keys.
__global__ __launch_bounds__(256) void dist_kernel(
    const float* __restrict__ emb, float* __restrict__ dist,
    uint32_t* __restrict__ keys0, uint32_t* __restrict__ keys1) {
  __shared__ float As[32][132];
  __shared__ float Bs[32][132];
  __shared__ float sqa[32], sqb[32];
  int bid = blockIdx.x;
  int ti = bid >> 4, tj = bid & 15;
  int t = threadIdx.x;

  const float4* ga = reinterpret_cast<const float4*>(emb + (size_t)ti * 32 * D);
  const float4* gb = reinterpret_cast<const float4*>(emb + (size_t)tj * 32 * D);
  #pragma unroll
  for (int k = 0; k < 4; ++k) {
    int idx = t + k * 256;
    int r = idx >> 5;
    int c4 = idx & 31;
    *reinterpret_cast<float4*>(&As[r][c4 * 4]) = ga[idx];
    *reinterpret_cast<float4*>(&Bs[r][c4 * 4]) = gb[idx];
  }
  __syncthreads();

  {
    int row = t >> 2, seg = t & 3;
    const float* src = (row < 32) ? &As[row][seg * 32] : &Bs[row - 32][seg * 32];
    float s = 0.f;
    #pragma unroll
    for (int m = 0; m < 32; ++m) { float v = src[m]; s += v * v; }
    s += __shfl_xor(s, 1);
    s += __shfl_xor(s, 2);
    if (seg == 0) { if (row < 32) sqa[row] = s; else sqb[row - 32] = s; }
  }

  int r = t >> 3, g = t & 7;
  const float4* A4 = reinterpret_cast<const float4*>(&As[r][0]);
  const float4* B0 = reinterpret_cast<const float4*>(&Bs[g][0]);
  const float4* B1 = reinterpret_cast<const float4*>(&Bs[g + 8][0]);
  const float4* B2 = reinterpret_cast<const float4*>(&Bs[g + 16][0]);
  const float4* B3 = reinterpret_cast<const float4*>(&Bs[g + 24][0]);
  float acc0 = 0.f, acc1 = 0.f, acc2 = 0.f, acc3 = 0.f;
  #pragma unroll 8
  for (int k4 = 0; k4 < 32; ++k4) {
    float4 a = A4[k4];
    float4 b0 = B0[k4], b1 = B1[k4], b2 = B2[k4], b3 = B3[k4];
    acc0 += a.x * b0.x + a.y * b0.y + a.z * b0.z + a.w * b0.w;
    acc1 += a.x * b1.x + a.y * b1.y + a.z * b1.z + a.w * b1.w;
    acc2 += a.x * b2.x + a.y * b2.y + a.z * b2.z + a.w * b2.w;
    acc3 += a.x * b3.x + a.y * b3.y + a.z * b3.z + a.w * b3.w;
  }
  __syncthreads();
  float sa = sqa[r];
  float* drow = dist + (size_t)(ti * 32 + r) * B + tj * 32;
  drow[g]      = sqrtf(fmaxf(sa + sqb[g]      - 2.f * acc0, 0.f));
  drow[g + 8]  = sqrtf(fmaxf(sa + sqb[g + 8]  - 2.f * acc1, 0.f));
  drow[g + 16] = sqrtf(fmaxf(sa + sqb[g + 16] - 2.f * acc2, 0.f));
  drow[g + 24] = sqrtf(fmaxf(sa + sqb[g + 24] - 2.f * acc3, 0.f));

  if (bid == 0) {
    #pragma unroll
    for (int pp = 0; pp < 2; ++pp) {
      int p = t + pp * 256;
      uint32_t i0 = 2u * (uint32_t)p, i1 = i0 + 1u;
      uint32_t a0, a1, b0, b1;
      if (p < 256) {
        threefry2x32(0u, 42u, i0, i0 + 512u, a0, a1);
        threefry2x32(0u, 42u, i1, i1 + 512u, b0, b1);
        keys0[p] = a0; keys1[p] = b0;
      } else {
        threefry2x32(0u, 42u, i0 - 512u, i0, a0, a1);
        threefry2x32(0u, 42u, i1 - 512u, i1, b0, b1);
        keys0[p] = a1; keys1[p] = b1;
      }
    }
  }
}

// K2 prep: one block per row. Builds the row's bucket-ordered packed-key
// array (skey_g), packed bucket ranges (range_g: start<<16|end), and hard_d.
// Block 0 additionally builds the per-label anchor lists.
__global__ __launch_bounds__(512) void prep_kernel(
    const float* __restrict__ dist, const int* __restrict__ labels,
    unsigned long long* __restrict__ skey_g, uint32_t* __restrict__ range_g,
    float* __restrict__ hard_d_g, unsigned short* __restrict__ lists,
    int* __restrict__ lcount) {
  __shared__ uint32_t hist[B];
  __shared__ uint32_t cur[B];
  __shared__ uint32_t wsum32[8], wprefix[8];
  __shared__ unsigned long long wmin[8];
  __shared__ unsigned short slab[B];
  int i = blockIdx.x;
  int t = threadIdx.x;
  int wave = t >> 6, lane = t & 63;
  hist[t] = 0u;
  slab[t] = (unsigned short)labels[t];
  float dv = dist[(size_t)i * B + t];
  __syncthreads();
  unsigned short lab_i = slab[i];
  bool neg = (slab[t] != lab_i);
  int b_t = (int)fminf(fmaxf(dv * 16.0f, 0.0f), 511.0f);
  if (neg) atomicAdd(&hist[b_t], 1u);
  // hard-negative argmin (ties -> lowest col): packed (fbits<<9 | col), min
  unsigned long long hkey =
      neg ? ((((unsigned long long)__float_as_uint(dv)) << 9) | (unsigned)t)
          : ~0ull;
  #pragma unroll
  for (int off = 32; off; off >>= 1) {
    unsigned long long o = __shfl_xor(hkey, off);
    if (o < hkey) hkey = o;
  }
  if (lane == 0) wmin[wave] = hkey;
  __syncthreads();  // hist + wmin ready
  if (t == 0) {
    unsigned long long m = wmin[0];
    #pragma unroll
    for (int w = 1; w < 8; ++w)
      if (wmin[w] < m) m = wmin[w];
    hard_d_g[i] = __uint_as_float((uint32_t)(m >> 9));  // NaN iff no negatives
  }
  // block-wide inclusive scan of hist
  uint32_t v = hist[t];
  #pragma unroll
  for (int d = 1; d < 64; d <<= 1) {
    uint32_t u = __shfl_up(v, d);
    if (lane >= (unsigned)d) v += u;
  }
  if (lane == 63) wsum32[wave] = v;
  __syncthreads();
  if (t == 0) {
    uint32_t acc = 0;
    #pragma unroll
    for (int w = 0; w < 8; ++w) { wprefix[w] = acc; acc += wsum32[w]; }
  }
  __syncthreads();
  uint32_t inc = v + wprefix[wave];
  uint32_t st = inc - hist[t];
  cur[t] = st;
  range_g[(size_t)i * B + t] = (st << 16) | inc;  // excl start | incl end
  __syncthreads();
  // scatter packed keys bucket-ordered (in-bucket order irrelevant:
  // selection is an order-independent max over unique packed keys)
  if (neg) {
    uint32_t pos = atomicAdd(&cur[b_t], 1u);
    skey_g[(size_t)i * B + pos] =
        (((unsigned long long)__float_as_uint(dv)) << 9) | (unsigned)t;
  }
  // block 0: per-label ascending anchor lists (wave w -> label w)
  if (i == 0) {
    unsigned long long lmask_lt = (1ull << lane) - 1ull;
    int n = 0;
    #pragma unroll
    for (int c = 0; c < 8; ++c) {
      int r = c * 64 + lane;
      bool vv = (slab[r] == (unsigned short)wave);
      unsigned long long mk = __ballot(vv);
      if (vv) lists[wave * B + n + __popcll(mk & lmask_lt)] = (unsigned short)r;
      n += __popcll(mk);
    }
    if (lane == 0) lcount[wave] = (n == B) ? 0 : n;  // n==B -> no negatives
  }
}

// K3 triplet: pure-wave, ZERO LDS, ZERO barriers. 8192 independent waves;
// wave (row i, slot s) walks anchors k = s, s+16, ... of i's label list.
// All row data (skey/range/dist/hard_d) read from L2; anchors independent,
// so the compiler can overlap whole iterations.
__global__ __launch_bounds__(256) void triplet_kernel(
    const float* __restrict__ dist, const int* __restrict__ labels,
    const uint32_t* __restrict__ keys0, const uint32_t* __restrict__ keys1,
    const unsigned long long* __restrict__ skey_g,
    const uint32_t* __restrict__ range_g, const float* __restrict__ hard_d_g,
    const unsigned short* __restrict__ lists, const int* __restrict__ lcount,
    double* __restrict__ partials, int* __restrict__ pcnt) {
  int wave = threadIdx.x >> 6, lane = threadIdx.x & 63;
  int slot = blockIdx.x * 4 + wave;
  int i = slot >> 4;
  int s = slot & 15;
  int lab = labels[i];
  int nlist = lcount[lab];
  const unsigned short* __restrict__ mylist = lists + lab * B;
  const unsigned long long* __restrict__ skey = skey_g + (size_t)i * B;
  const uint32_t* __restrict__ range = range_g + (size_t)i * B;
  const float* __restrict__ drow = dist + (size_t)i * B;
  float hard_d = hard_d_g[i];
  uint32_t rowbase = (uint32_t)((i & 255) * B);
  bool take_hi = (i >= 256);
  double wsum = 0.0;
  unsigned int wcnt = 0;

#define LOAD_ANCHOR(KK, KP0, KP1, PD, ST, EN, LOK, HIK) { \
    int p_ = __builtin_amdgcn_readfirstlane((int)mylist[KK]); \
    KP0 = keys0[p_]; KP1 = keys1[p_]; \
    PD = (p_ == i) ? -2.0f : drow[p_]; /* sentinel: empty window */ \
    float hf_ = PD + 1.0f; /* margin = 1.0 */ \
    int lob_ = (int)fminf(fmaxf(PD * 16.0f, 0.0f), 511.0f); \
    int hib_ = (int)fminf(fmaxf(hf_ * 16.0f, 0.0f), 511.0f); \
    ST = (int)(range[lob_] >> 16); \
    EN = (int)(range[hib_] & 0xFFFFu); \
    LOK = (((unsigned long long)__float_as_uint(PD)) << 9) | 511u; \
    HIK = ((unsigned long long)__float_as_uint(hf_)) << 9; }

// One drain step of NCH chains starting at superset index c0 (+64 per chain).
#define DRAIN(NCH) { \
    uint32_t xs0[NCH], xs1[NCH], js[NCH]; bool vd[NCH]; \
    _Pragma("unroll") for (int q = 0; q < NCH; ++q) { \
      int c_ = c0 + q * 64; \
      unsigned long long kv = skey[(c_ < end) ? c_ : start]; \
      vd[q] = (c_ < end) && (kv > lokey) && (kv < hikey); \
      js[q] = (uint32_t)(kv & 0x1FFu); \
      xs0[q] = rowbase + js[q]; \
      xs1[q] = rowbase + js[q] + HALFC; \
    } \
    tf_multi<NCH>(kp0, kp1, xs0, xs1); \
    _Pragma("unroll") for (int q = 0; q < NCH; ++q) { \
      uint32_t kk = ((take_hi ? xs1[q] : xs0[q]) & 0xFFFFFE00u) | \
                    (511u - js[q]); \
      if (vd[q] && kk > best) best = kk; \
    } }

  int k = s;
  uint32_t kpN0 = 0, kpN1 = 0;
  float pdN = -2.0f;
  int stN = 0, enN = 0;
  unsigned long long lokN = 0, hikN = 0;
  if (k < nlist) LOAD_ANCHOR(k, kpN0, kpN1, pdN, stN, enN, lokN, hikN);

  while (k < nlist) {
    uint32_t kp0 = kpN0, kp1 = kpN1;
    float pos_d = pdN;
    int start = stN, end = enN;
    unsigned long long lokey = lokN, hikey = hikN;
    int kn = k + 16;
    if (kn < nlist) LOAD_ANCHOR(kn, kpN0, kpN1, pdN, stN, enN, lokN, hikN);

    float tl;
    if (end > start) {
      // packed key: (bits23 << 9) | (511 - j); max -> max bits, tie -> min j
      uint32_t best = 0u;
      int nch = (end - start + 63) >> 6;  // wave-uniform
      int c0 = start + lane;
      while (nch > 4) { DRAIN(4); c0 += 256; nch -= 4; }
      switch (nch) {
        case 4: DRAIN(4); break;
        case 3: DRAIN(3); break;
        case 2: DRAIN(2); break;
        default: DRAIN(1); break;
      }
      best = dpp_max_all(best);
      if (best) {
        int idx = 511 - (int)(best & 0x1FFu);
        tl = pos_d - drow[idx] + 1.0f;
      } else {
        tl = pos_d - hard_d + 1.0f;
      }
    } else {
      tl = pos_d - hard_d + 1.0f;  // sentinel pos_d=-2 -> tl<0, dropped
    }
    if (tl > 0.f) { wsum += (double)tl; wcnt++; }
    k = kn;
  }
#undef LOAD_ANCHOR
#undef DRAIN

  if (lane == 0) {
    partials[slot] = wsum;
    pcnt[slot] = (int)wcnt;
  }
}

// K4: deterministic fixed-order reduction of the 8192 wave partials.
__global__ __launch_bounds__(256) void finalize_kernel(
    const double* __restrict__ partials, const int* __restrict__ pcnt,
    float* __restrict__ out) {
  __shared__ double ss[256];
  __shared__ int sc[256];
  int t = threadIdx.x;
  double s = 0.0;
  int c = 0;
  for (int k = t; k < NPART; k += 256) { s += partials[k]; c += pcnt[k]; }
  ss[t] = s; sc[t] = c;
  __syncthreads();
  for (int st = 128; st; st >>= 1) {
    if (t < st) { ss[t] += ss[t + st]; sc[t] += sc[t + st]; }
    __syncthreads();
  }
  if (t == 0) out[0] = sc[0] ? (float)(ss[0] / (double)sc[0]) : 0.0f;
}

extern "C" void kernel_launch(void* const* d_in, const int* in_sizes, int n_in,
                              void* d_out, int out_size, void* d_ws, size_t ws_size,
                              hipStream_t stream) {
  const float* emb = (const float*)d_in[0];
  const int* labels = (const int*)d_in[1];
  float* out = (float*)d_out;
  char* ws = (char*)d_ws;

  float* dist = (float*)ws;                                   // 1 MB
  unsigned long long* skey_g = (unsigned long long*)(ws + (1u << 20));  // 2 MB
  uint32_t* range_g = (uint32_t*)(ws + 3 * (1u << 20));       // 1 MB
  uint32_t* keys0 = (uint32_t*)(ws + 4 * (1u << 20));         // 2 KB
  uint32_t* keys1 = (uint32_t*)(ws + 4 * (1u << 20) + 2048);  // 2 KB
  unsigned short* lists = (unsigned short*)(ws + 4 * (1u << 20) + 4096);  // 8 KB
  int* lcount = (int*)(ws + 4 * (1u << 20) + 12288);          // 64 B
  float* hard_d_g = (float*)(ws + 4 * (1u << 20) + 12352);    // 2 KB
  double* partials = (double*)(ws + 4 * (1u << 20) + 16384);  // 64 KB
  int* pcnt = (int*)(ws + 4 * (1u << 20) + 16384 + 65536);    // 32 KB

  dist_kernel<<<256, 256, 0, stream>>>(emb, dist, keys0, keys1);
  prep_kernel<<<B, 512, 0, stream>>>(dist, labels, skey_g, range_g, hard_d_g,
                                     lists, lcount);
  triplet_kernel<<<2048, 256, 0, stream>>>(dist, labels, keys0, keys1, skey_g,
                                           range_g, hard_d_g, lists, lcount,
                                           partials, pcnt);
  finalize_kernel<<<1, 256, 0, stream>>>(partials, pcnt, out);
}

// Round 18
// 47.908 us; speedup vs baseline: 1.0013x; 1.0010x over previous
//
#include <hip/hip_runtime.h>
#include <stdint.h>

#define B 512
#define D 128
#define HALFC 131072u
#define NPART 8192  /* 512 rows x 16 wave-slots */

__device__ __forceinline__ uint32_t rotl32(uint32_t x, uint32_t r) {
  return (x << r) | (x >> (32u - r));
}

// Exact JAX/XLA threefry2x32 (20 rounds, key-schedule injections every 4).
__device__ __forceinline__ void threefry2x32(uint32_t k0, uint32_t k1,
                                             uint32_t x0, uint32_t x1,
                                             uint32_t& y0, uint32_t& y1) {
  uint32_t k2 = k0 ^ k1 ^ 0x1BD11BDAu;
  x0 += k0; x1 += k1;
#define TF_R(r) { x0 += x1; x1 = rotl32(x1, r); x1 ^= x0; }
  TF_R(13) TF_R(15) TF_R(26) TF_R(6)
  x0 += k1; x1 += k2 + 1u;
  TF_R(17) TF_R(29) TF_R(16) TF_R(24)
  x0 += k2; x1 += k0 + 2u;
  TF_R(13) TF_R(15) TF_R(26) TF_R(6)
  x0 += k0; x1 += k1 + 3u;
  TF_R(17) TF_R(29) TF_R(16) TF_R(24)
  x0 += k1; x1 += k2 + 4u;
  TF_R(13) TF_R(15) TF_R(26) TF_R(6)
  x0 += k2; x1 += k0 + 5u;
#undef TF_R
  y0 = x0; y1 = x1;
}

// N independent threefry chains, fully unrolled in registers.
template <int N>
__device__ __forceinline__ void tf_multi(uint32_t k0, uint32_t k1,
                                         uint32_t (&x0)[N], uint32_t (&x1)[N]) {
  uint32_t k2 = k0 ^ k1 ^ 0x1BD11BDAu;
#pragma unroll
  for (int q = 0; q < N; ++q) { x0[q] += k0; x1[q] += k1; }
#define TFM_R(r) \
  _Pragma("unroll") for (int q = 0; q < N; ++q) { \
    x0[q] += x1[q]; x1[q] = rotl32(x1[q], r); x1[q] ^= x0[q]; }
#define TFM_INJ(a, b, c) \
  _Pragma("unroll") for (int q = 0; q < N; ++q) { x0[q] += a; x1[q] += b + c; }
  TFM_R(13) TFM_R(15) TFM_R(26) TFM_R(6)
  TFM_INJ(k1, k2, 1u)
  TFM_R(17) TFM_R(29) TFM_R(16) TFM_R(24)
  TFM_INJ(k2, k0, 2u)
  TFM_R(13) TFM_R(15) TFM_R(26) TFM_R(6)
  TFM_INJ(k0, k1, 3u)
  TFM_R(17) TFM_R(29) TFM_R(16) TFM_R(24)
  TFM_INJ(k1, k2, 4u)
  TFM_R(13) TFM_R(15) TFM_R(26) TFM_R(6)
  TFM_INJ(k2, k0, 5u)
#undef TFM_R
#undef TFM_INJ
}

// 64-lane max-reduce via DPP: row_shr 1/2/4/8 then row_bcast 15/31.
__device__ __forceinline__ uint32_t dpp_max_all(uint32_t x) {
  uint32_t t;
#define DPP_STEP(ctrl) \
  t = (uint32_t)__builtin_amdgcn_update_dpp(0, (int)x, ctrl, 0xf, 0xf, true); \
  x = (t > x) ? t : x;
  DPP_STEP(0x111)  // row_shr:1
  DPP_STEP(0x112)  // row_shr:2
  DPP_STEP(0x114)  // row_shr:4
  DPP_STEP(0x118)  // row_shr:8
  DPP_STEP(0x142)  // row_bcast:15
  DPP_STEP(0x143)  // row_bcast:31
#undef DPP_STEP
  return (uint32_t)__builtin_amdgcn_readlane((int)x, 63);
}

// K1: tiled dist "GEMM" (unchanged). Block 0 computes the 512 anchor keys.
__global__ __launch_bounds__(256) void dist_kernel(
    const float* __restrict__ emb, float* __restrict__ dist,
    uint32_t* __restrict__ keys0, uint32_t* __restrict__ keys1) {
  __shared__ float As[32][132];
  __shared__ float Bs[32][132];
  __shared__ float sqa[32], sqb[32];
  int bid = blockIdx.x;
  int ti = bid >> 4, tj = bid & 15;
  int t = threadIdx.x;

  const float4* ga = reinterpret_cast<const float4*>(emb + (size_t)ti * 32 * D);
  const float4* gb = reinterpret_cast<const float4*>(emb + (size_t)tj * 32 * D);
  #pragma unroll
  for (int k = 0; k < 4; ++k) {
    int idx = t + k * 256;
    int r = idx >> 5;
    int c4 = idx & 31;
    *reinterpret_cast<float4*>(&As[r][c4 * 4]) = ga[idx];
    *reinterpret_cast<float4*>(&Bs[r][c4 * 4]) = gb[idx];
  }
  __syncthreads();

  {
    int row = t >> 2, seg = t & 3;
    const float* src = (row < 32) ? &As[row][seg * 32] : &Bs[row - 32][seg * 32];
    float s = 0.f;
    #pragma unroll
    for (int m = 0; m < 32; ++m) { float v = src[m]; s += v * v; }
    s += __shfl_xor(s, 1);
    s += __shfl_xor(s, 2);
    if (seg == 0) { if (row < 32) sqa[row] = s; else sqb[row - 32] = s; }
  }

  int r = t >> 3, g = t & 7;
  const float4* A4 = reinterpret_cast<const float4*>(&As[r][0]);
  const float4* B0 = reinterpret_cast<const float4*>(&Bs[g][0]);
  const float4* B1 = reinterpret_cast<const float4*>(&Bs[g + 8][0]);
  const float4* B2 = reinterpret_cast<const float4*>(&Bs[g + 16][0]);
  const float4* B3 = reinterpret_cast<const float4*>(&Bs[g + 24][0]);
  float acc0 = 0.f, acc1 = 0.f, acc2 = 0.f, acc3 = 0.f;
  #pragma unroll 8
  for (int k4 = 0; k4 < 32; ++k4) {
    float4 a = A4[k4];
    float4 b0 = B0[k4], b1 = B1[k4], b2 = B2[k4], b3 = B3[k4];
    acc0 += a.x * b0.x + a.y * b0.y + a.z * b0.z + a.w * b0.w;
    acc1 += a.x * b1.x + a.y * b1.y + a.z * b1.z + a.w * b1.w;
    acc2 += a.x * b2.x + a.y * b2.y + a.z * b2.z + a.w * b2.w;
    acc3 += a.x * b3.x + a.y * b3.y + a.z * b3.z + a.w * b3.w;
  }
  __syncthreads();
  float sa = sqa[r];
  float* drow = dist + (size_t)(ti * 32 + r) * B + tj * 32;
  drow[g]      = sqrtf(fmaxf(sa + sqb[g]      - 2.f * acc0, 0.f));
  drow[g + 8]  = sqrtf(fmaxf(sa + sqb[g + 8]  - 2.f * acc1, 0.f));
  drow[g + 16] = sqrtf(fmaxf(sa + sqb[g + 16] - 2.f * acc2, 0.f));
  drow[g + 24] = sqrtf(fmaxf(sa + sqb[g + 24] - 2.f * acc3, 0.f));

  if (bid == 0) {
    #pragma unroll
    for (int pp = 0; pp < 2; ++pp) {
      int p = t + pp * 256;
      uint32_t i0 = 2u * (uint32_t)p, i1 = i0 + 1u;
      uint32_t a0, a1, b0, b1;
      if (p < 256) {
        threefry2x32(0u, 42u, i0, i0 + 512u, a0, a1);
        threefry2x32(0u, 42u, i1, i1 + 512u, b0, b1);
        keys0[p] = a0; keys1[p] = b0;
      } else {
        threefry2x32(0u, 42u, i0 - 512u, i0, a0, a1);
        threefry2x32(0u, 42u, i1 - 512u, i1, b0, b1);
        keys0[p] = a1; keys1[p] = b1;
      }
    }
  }
}

// K2 prep: one block per row. Builds the row's bucket-ordered packed-key
// array (skey_g), packed bucket ranges (range_g: start<<16|end), and hard_d.
// Block 0 additionally builds the per-label anchor lists.
__global__ __launch_bounds__(512) void prep_kernel(
    const float* __restrict__ dist, const int* __restrict__ labels,
    unsigned long long* __restrict__ skey_g, uint32_t* __restrict__ range_g,
    float* __restrict__ hard_d_g, unsigned short* __restrict__ lists,
    int* __restrict__ lcount) {
  __shared__ uint32_t hist[B];
  __shared__ uint32_t cur[B];
  __shared__ uint32_t wsum32[8], wprefix[8];
  __shared__ unsigned long long wmin[8];
  __shared__ unsigned short slab[B];
  int i = blockIdx.x;
  int t = threadIdx.x;
  int wave = t >> 6, lane = t & 63;
  hist[t] = 0u;
  slab[t] = (unsigned short)labels[t];
  float dv = dist[(size_t)i * B + t];
  __syncthreads();
  unsigned short lab_i = slab[i];
  bool neg = (slab[t] != lab_i);
  int b_t = (int)fminf(fmaxf(dv * 16.0f, 0.0f), 511.0f);
  if (neg) atomicAdd(&hist[b_t], 1u);
  // hard-negative argmin (ties -> lowest col): packed (fbits<<9 | col), min
  unsigned long long hkey =
      neg ? ((((unsigned long long)__float_as_uint(dv)) << 9) | (unsigned)t)
          : ~0ull;
  #pragma unroll
  for (int off = 32; off; off >>= 1) {
    unsigned long long o = __shfl_xor(hkey, off);
    if (o < hkey) hkey = o;
  }
  if (lane == 0) wmin[wave] = hkey;
  __syncthreads();  // hist + wmin ready
  if (t == 0) {
    unsigned long long m = wmin[0];
    #pragma unroll
    for (int w = 1; w < 8; ++w)
      if (wmin[w] < m) m = wmin[w];
    hard_d_g[i] = __uint_as_float((uint32_t)(m >> 9));  // NaN iff no negatives
  }
  // block-wide inclusive scan of hist
  uint32_t v = hist[t];
  #pragma unroll
  for (int d = 1; d < 64; d <<= 1) {
    uint32_t u = __shfl_up(v, d);
    if (lane >= (unsigned)d) v += u;
  }
  if (lane == 63) wsum32[wave] = v;
  __syncthreads();
  if (t == 0) {
    uint32_t acc = 0;
    #pragma unroll
    for (int w = 0; w < 8; ++w) { wprefix[w] = acc; acc += wsum32[w]; }
  }
  __syncthreads();
  uint32_t inc = v + wprefix[wave];
  uint32_t st = inc - hist[t];
  cur[t] = st;
  range_g[(size_t)i * B + t] = (st << 16) | inc;  // excl start | incl end
  __syncthreads();
  // scatter packed keys bucket-ordered (in-bucket order irrelevant:
  // selection is an order-independent max over unique packed keys)
  if (neg) {
    uint32_t pos = atomicAdd(&cur[b_t], 1u);
    skey_g[(size_t)i * B + pos] =
        (((unsigned long long)__float_as_uint(dv)) << 9) | (unsigned)t;
  }
  // block 0: per-label ascending anchor lists (wave w -> label w)
  if (i == 0) {
    unsigned long long lmask_lt = (1ull << lane) - 1ull;
    int n = 0;
    #pragma unroll
    for (int c = 0; c < 8; ++c) {
      int r = c * 64 + lane;
      bool vv = (slab[r] == (unsigned short)wave);
      unsigned long long mk = __ballot(vv);
      if (vv) lists[wave * B + n + __popcll(mk & lmask_lt)] = (unsigned short)r;
      n += __popcll(mk);
    }
    if (lane == 0) lcount[wave] = (n == B) ? 0 : n;  // n==B -> no negatives
  }
}

// K3 triplet: pure-wave, ZERO LDS, ZERO barriers. 8192 independent waves;
// wave (row i, slot s) walks anchors k = s, s+16, ... of i's label list.
// All row data (skey/range/dist/hard_d) read from L2; anchors independent,
// so the compiler can overlap whole iterations.
__global__ __launch_bounds__(256) void triplet_kernel(
    const float* __restrict__ dist, const int* __restrict__ labels,
    const uint32_t* __restrict__ keys0, const uint32_t* __restrict__ keys1,
    const unsigned long long* __restrict__ skey_g,
    const uint32_t* __restrict__ range_g, const float* __restrict__ hard_d_g,
    const unsigned short* __restrict__ lists, const int* __restrict__ lcount,
    double* __restrict__ partials, int* __restrict__ pcnt) {
  int wave = threadIdx.x >> 6, lane = threadIdx.x & 63;
  int slot = blockIdx.x * 4 + wave;
  int i = slot >> 4;
  int s = slot & 15;
  int lab = labels[i];
  int nlist = lcount[lab];
  const unsigned short* __restrict__ mylist = lists + lab * B;
  const unsigned long long* __restrict__ skey = skey_g + (size_t)i * B;
  const uint32_t* __restrict__ range = range_g + (size_t)i * B;
  const float* __restrict__ drow = dist + (size_t)i * B;
  float hard_d = hard_d_g[i];
  uint32_t rowbase = (uint32_t)((i & 255) * B);
  bool take_hi = (i >= 256);
  double wsum = 0.0;
  unsigned int wcnt = 0;

#define LOAD_ANCHOR(KK, KP0, KP1, PD, ST, EN, LOK, HIK) { \
    int p_ = __builtin_amdgcn_readfirstlane((int)mylist[KK]); \
    KP0 = keys0[p_]; KP1 = keys1[p_]; \
    PD = (p_ == i) ? -2.0f : drow[p_]; /* sentinel: empty window */ \
    float hf_ = PD + 1.0f; /* margin = 1.0 */ \
    int lob_ = (int)fminf(fmaxf(PD * 16.0f, 0.0f), 511.0f); \
    int hib_ = (int)fminf(fmaxf(hf_ * 16.0f, 0.0f), 511.0f); \
    ST = (int)(range[lob_] >> 16); \
    EN = (int)(range[hib_] & 0xFFFFu); \
    LOK = (((unsigned long long)__float_as_uint(PD)) << 9) | 511u; \
    HIK = ((unsigned long long)__float_as_uint(hf_)) << 9; }

// One drain step of NCH chains starting at superset index c0 (+64 per chain).
#define DRAIN(NCH) { \
    uint32_t xs0[NCH], xs1[NCH], js[NCH]; bool vd[NCH]; \
    _Pragma("unroll") for (int q = 0; q < NCH; ++q) { \
      int c_ = c0 + q * 64; \
      unsigned long long kv = skey[(c_ < end) ? c_ : start]; \
      vd[q] = (c_ < end) && (kv > lokey) && (kv < hikey); \
      js[q] = (uint32_t)(kv & 0x1FFu); \
      xs0[q] = rowbase + js[q]; \
      xs1[q] = rowbase + js[q] + HALFC; \
    } \
    tf_multi<NCH>(kp0, kp1, xs0, xs1); \
    _Pragma("unroll") for (int q = 0; q < NCH; ++q) { \
      uint32_t kk = ((take_hi ? xs1[q] : xs0[q]) & 0xFFFFFE00u) | \
                    (511u - js[q]); \
      if (vd[q] && kk > best) best = kk; \
    } }

  int k = s;
  uint32_t kpN0 = 0, kpN1 = 0;
  float pdN = -2.0f;
  int stN = 0, enN = 0;
  unsigned long long lokN = 0, hikN = 0;
  if (k < nlist) LOAD_ANCHOR(k, kpN0, kpN1, pdN, stN, enN, lokN, hikN);

  while (k < nlist) {
    uint32_t kp0 = kpN0, kp1 = kpN1;
    float pos_d = pdN;
    int start = stN, end = enN;
    unsigned long long lokey = lokN, hikey = hikN;
    int kn = k + 16;
    if (kn < nlist) LOAD_ANCHOR(kn, kpN0, kpN1, pdN, stN, enN, lokN, hikN);

    float tl;
    if (end > start) {
      // packed key: (bits23 << 9) | (511 - j); max -> max bits, tie -> min j
      uint32_t best = 0u;
      int nch = (end - start + 63) >> 6;  // wave-uniform
      int c0 = start + lane;
      while (nch > 4) { DRAIN(4); c0 += 256; nch -= 4; }
      switch (nch) {
        case 4: DRAIN(4); break;
        case 3: DRAIN(3); break;
        case 2: DRAIN(2); break;
        default: DRAIN(1); break;
      }
      best = dpp_max_all(best);
      if (best) {
        int idx = 511 - (int)(best & 0x1FFu);
        tl = pos_d - drow[idx] + 1.0f;
      } else {
        tl = pos_d - hard_d + 1.0f;
      }
    } else {
      tl = pos_d - hard_d + 1.0f;  // sentinel pos_d=-2 -> tl<0, dropped
    }
    if (tl > 0.f) { wsum += (double)tl; wcnt++; }
    k = kn;
  }
#undef LOAD_ANCHOR
#undef DRAIN

  if (lane == 0) {
    partials[slot] = wsum;
    pcnt[slot] = (int)wcnt;
  }
}

// K4: deterministic fixed-order reduction of the 8192 wave partials.
__global__ __launch_bounds__(256) void finalize_kernel(
    const double* __restrict__ partials, const int* __restrict__ pcnt,
    float* __restrict__ out) {
  __shared__ double ss[256];
  __shared__ int sc[256];
  int t = threadIdx.x;
  double s = 0.0;
  int c = 0;
  for (int k = t; k < NPART; k += 256) { s += partials[k]; c += pcnt[k]; }
  ss[t] = s; sc[t] = c;
  __syncthreads();
  for (int st = 128; st; st >>= 1) {
    if (t < st) { ss[t] += ss[t + st]; sc[t] += sc[t + st]; }
    __syncthreads();
  }
  if (t == 0) out[0] = sc[0] ? (float)(ss[0] / (double)sc[0]) : 0.0f;
}

extern "C" void kernel_launch(void* const* d_in, const int* in_sizes, int n_in,
                              void* d_out, int out_size, void* d_ws, size_t ws_size,
                              hipStream_t stream) {
  const float* emb = (const float*)d_in[0];
  const int* labels = (const int*)d_in[1];
  float* out = (float*)d_out;
  char* ws = (char*)d_ws;

  float* dist = (float*)ws;                                   // 1 MB
  unsigned long long* skey_g = (unsigned long long*)(ws + (1u << 20));  // 2 MB
  uint32_t* range_g = (uint32_t*)(ws + 3 * (1u << 20));       // 1 MB
  uint32_t* keys0 = (uint32_t*)(ws + 4 * (1u << 20));         // 2 KB
  uint32_t* keys1 = (uint32_t*)(ws + 4 * (1u << 20) + 2048);  // 2 KB
  unsigned short* lists = (unsigned short*)(ws + 4 * (1u << 20) + 4096);  // 8 KB
  int* lcount = (int*)(ws + 4 * (1u << 20) + 12288);          // 64 B
  float* hard_d_g = (float*)(ws + 4 * (1u << 20) + 12352);    // 2 KB
  double* partials = (double*)(ws + 4 * (1u << 20) + 16384);  // 64 KB
  int* pcnt = (int*)(ws + 4 * (1u << 20) + 16384 + 65536);    // 32 KB

  dist_kernel<<<256, 256, 0, stream>>>(emb, dist, keys0, keys1);
  prep_kernel<<<B, 512, 0, stream>>>(dist, labels, skey_g, range_g, hard_d_g,
                                     lists, lcount);
  triplet_kernel<<<2048, 256, 0, stream>>>(dist, labels, keys0, keys1, skey_g,
                                           range_g, hard_d_g, lists, lcount,
                                           partials, pcnt);
  finalize_kernel<<<1, 256, 0, stream>>>(partials, pcnt, out);
}